// Round 2
// baseline (19548.683 us; speedup 1.0000x reference)
//
#include <hip/hip_runtime.h>
#include <hip/hip_bf16.h>

#define B 512
#define S 64
#define H 1024
#define O 1024
#define T 128
#define ATT 64

typedef __bf16 bf16;
typedef __bf16 bf16x8 __attribute__((ext_vector_type(8)));
typedef __bf16 bf16x4 __attribute__((ext_vector_type(4)));
typedef float f32x4 __attribute__((ext_vector_type(4)));

static __device__ __forceinline__ float bf2f(bf16 b) {
    unsigned short s = __builtin_bit_cast(unsigned short, b);
    unsigned int u = ((unsigned int)s) << 16;
    return __builtin_bit_cast(float, u);
}
static __device__ __forceinline__ bf16 f2bf(float f) {
    unsigned int u = __builtin_bit_cast(unsigned int, f);
    unsigned int r = (u + 0x7fffu + ((u >> 16) & 1u)) >> 16;
    return __builtin_bit_cast(bf16, (unsigned short)r);
}

// ---------------------------------------------------------------------------
// Attention logits + softmax: logits = h @ W^T + bias (K=1024), softmax rows.
// grid (1, B/16), block 128 (2 waves share the 16 A-rows, split N 2x32).
// ---------------------------------------------------------------------------
__global__ __launch_bounds__(128) void attn_logits_kernel(
    const bf16* __restrict__ h, const bf16* __restrict__ W, int ldw,
    const float* __restrict__ bias, bf16* __restrict__ attn_w) {
    __shared__ float lg[16][64];
    const int tid = threadIdx.x;
    const int wn = tid >> 6, lane = tid & 63;
    const int quad = lane >> 4, r = lane & 15;
    const int kq = quad * 8;

    const int m0 = blockIdx.y * 16 + r;
    const int n0 = wn * 32;

    const bf16* hrow = h + (long)m0 * H + kq;
    const bf16* w0 = W + (long)(n0 + r) * ldw + kq;
    const bf16* w1 = W + (long)(n0 + 16 + r) * ldw + kq;

    f32x4 acc0 = {0.f, 0.f, 0.f, 0.f}, acc1 = {0.f, 0.f, 0.f, 0.f};
#pragma unroll 4
    for (int k = 0; k < H; k += 32) {
        bf16x8 av = *(const bf16x8*)(hrow + k);
        bf16x8 b0 = *(const bf16x8*)(w0 + k);
        bf16x8 b1 = *(const bf16x8*)(w1 + k);
        acc0 = __builtin_amdgcn_mfma_f32_16x16x32_bf16(av, b0, acc0, 0, 0, 0);
        acc1 = __builtin_amdgcn_mfma_f32_16x16x32_bf16(av, b1, acc1, 0, 0, 0);
    }

    const int mloc = quad * 4;
#pragma unroll
    for (int reg = 0; reg < 4; ++reg) {
        lg[mloc + reg][n0 + r] = acc0[reg] + bias[n0 + r];
        lg[mloc + reg][n0 + 16 + r] = acc1[reg] + bias[n0 + 16 + r];
    }
    __syncthreads();

    if (tid < 16) {
        const int row = tid;
        float mx = -1e30f;
#pragma unroll
        for (int s = 0; s < 64; ++s) mx = fmaxf(mx, lg[row][s]);
        float sum = 0.f;
#pragma unroll
        for (int s = 0; s < 64; ++s) sum += __expf(lg[row][s] - mx);
        const float inv = 1.f / sum;
        const long gb = (long)(blockIdx.y * 16 + row) * 64;
#pragma unroll
        for (int s = 0; s < 64; ++s)
            attn_w[gb + s] = f2bf(__expf(lg[row][s] - mx) * inv);
    }
}

// ---------------------------------------------------------------------------
// attn[b,d] = sum_s w[b,s] * enc[b,s,d].  grid = B, block 256, 4 d's/thread.
// ---------------------------------------------------------------------------
__global__ __launch_bounds__(256) void attn_apply_kernel(
    const bf16* __restrict__ attn_w, const bf16* __restrict__ enc,
    bf16* __restrict__ attn_out) {
    __shared__ float w[64];
    const int b = blockIdx.x;
    const int t = threadIdx.x;
    if (t < 64) w[t] = bf2f(attn_w[b * 64 + t]);
    __syncthreads();
    const bf16* e = enc + (long)b * (S * 1024) + 4 * t;
    float a0 = 0.f, a1 = 0.f, a2 = 0.f, a3 = 0.f;
#pragma unroll 8
    for (int s = 0; s < S; ++s) {
        bf16x4 v = *(const bf16x4*)(e + (long)s * 1024);
        const float ws = w[s];
        a0 += ws * bf2f(v[0]); a1 += ws * bf2f(v[1]);
        a2 += ws * bf2f(v[2]); a3 += ws * bf2f(v[3]);
    }
    bf16x4 o = {f2bf(a0), f2bf(a1), f2bf(a2), f2bf(a3)};
    *(bf16x4*)(attn_out + (long)b * 1024 + 4 * t) = o;
}

// ---------------------------------------------------------------------------
// combine: gru_in = relu(A0@W0^T [K0] + A1@W1^T [1024] + bias), out bf16.
// W0 = Wd (ld H). grid (H/64, B/32), 256 thr.
// ---------------------------------------------------------------------------
template <int K0>
__global__ __launch_bounds__(256) void combine_kernel(
    const bf16* __restrict__ A0, const bf16* __restrict__ W0,
    const bf16* __restrict__ A1, const bf16* __restrict__ W1, int ldw1,
    const float* __restrict__ bias, bf16* __restrict__ Cout) {
    const int tid = threadIdx.x;
    const int wave = tid >> 6, lane = tid & 63;
    const int wm = wave >> 1, wn = wave & 1;
    const int quad = lane >> 4, r = lane & 15;
    const int kq = quad * 8;

    const int m0 = blockIdx.y * 32 + wm * 16 + r;
    const int n0 = blockIdx.x * 64 + wn * 32;

    f32x4 acc0 = {0.f, 0.f, 0.f, 0.f}, acc1 = {0.f, 0.f, 0.f, 0.f};

    if (K0 > 0) {
        const bf16* a = A0 + (long)m0 * H + kq;
        const bf16* w0 = W0 + (long)(n0 + r) * H + kq;
        const bf16* w1 = W0 + (long)(n0 + 16 + r) * H + kq;
#pragma unroll 4
        for (int k = 0; k < K0; k += 32) {
            bf16x8 av = *(const bf16x8*)(a + k);
            bf16x8 b0 = *(const bf16x8*)(w0 + k);
            bf16x8 b1 = *(const bf16x8*)(w1 + k);
            acc0 = __builtin_amdgcn_mfma_f32_16x16x32_bf16(av, b0, acc0, 0, 0, 0);
            acc1 = __builtin_amdgcn_mfma_f32_16x16x32_bf16(av, b1, acc1, 0, 0, 0);
        }
    }
    {
        const bf16* a = A1 + (long)m0 * H + kq;
        const bf16* w0 = W1 + (long)(n0 + r) * ldw1 + kq;
        const bf16* w1 = W1 + (long)(n0 + 16 + r) * ldw1 + kq;
#pragma unroll 4
        for (int k = 0; k < H; k += 32) {
            bf16x8 av = *(const bf16x8*)(a + k);
            bf16x8 b0 = *(const bf16x8*)(w0 + k);
            bf16x8 b1 = *(const bf16x8*)(w1 + k);
            acc0 = __builtin_amdgcn_mfma_f32_16x16x32_bf16(av, b0, acc0, 0, 0, 0);
            acc1 = __builtin_amdgcn_mfma_f32_16x16x32_bf16(av, b1, acc1, 0, 0, 0);
        }
    }

    const int mbase = blockIdx.y * 32 + wm * 16 + quad * 4;
    const int nA = n0 + r, nB = n0 + 16 + r;
    const float biasA = bias[nA], biasB = bias[nB];
#pragma unroll
    for (int reg = 0; reg < 4; ++reg) {
        const int m = mbase + reg;
        Cout[(long)m * H + nA] = f2bf(fmaxf(acc0[reg] + biasA, 0.f));
        Cout[(long)m * H + nB] = f2bf(fmaxf(acc1[reg] + biasB, 0.f));
    }
}

// ---------------------------------------------------------------------------
// fc_out GEMM: out = A@Wo^T + bo (fp32 out). grid (O/64, M/32).
// REMAP: row m -> (b = m&511, t = m>>9), out[b*T*O + t*O + n].
// ---------------------------------------------------------------------------
template <bool REMAP>
__global__ __launch_bounds__(256) void fc_kernel(
    const bf16* __restrict__ A, const bf16* __restrict__ W,
    const float* __restrict__ bias, float* __restrict__ out, long ldc) {
    const int tid = threadIdx.x;
    const int wave = tid >> 6, lane = tid & 63;
    const int wm = wave >> 1, wn = wave & 1;
    const int quad = lane >> 4, r = lane & 15;
    const int kq = quad * 8;

    const int m0 = blockIdx.y * 32 + wm * 16 + r;
    const int n0 = blockIdx.x * 64 + wn * 32;

    const bf16* a = A + (long)m0 * H + kq;
    const bf16* w0 = W + (long)(n0 + r) * H + kq;
    const bf16* w1 = W + (long)(n0 + 16 + r) * H + kq;

    f32x4 acc0 = {0.f, 0.f, 0.f, 0.f}, acc1 = {0.f, 0.f, 0.f, 0.f};
#pragma unroll 4
    for (int k = 0; k < H; k += 32) {
        bf16x8 av = *(const bf16x8*)(a + k);
        bf16x8 b0 = *(const bf16x8*)(w0 + k);
        bf16x8 b1 = *(const bf16x8*)(w1 + k);
        acc0 = __builtin_amdgcn_mfma_f32_16x16x32_bf16(av, b0, acc0, 0, 0, 0);
        acc1 = __builtin_amdgcn_mfma_f32_16x16x32_bf16(av, b1, acc1, 0, 0, 0);
    }

    const int mbase = blockIdx.y * 32 + wm * 16 + quad * 4;
    const int nA = n0 + r, nB = n0 + 16 + r;
    const float biasA = bias[nA], biasB = bias[nB];
#pragma unroll
    for (int reg = 0; reg < 4; ++reg) {
        const int m = mbase + reg;
        long base;
        if (REMAP)
            base = (long)(m & (B - 1)) * ((long)T * O) + (long)(m >> 9) * O;
        else
            base = (long)m * ldc;
        out[base + nA] = acc0[reg] + biasA;
        out[base + nB] = acc1[reg] + biasB;
    }
}

// ---------------------------------------------------------------------------
// Fused GRU: 6 GEMM accumulations + gate math. grid (H/64, B/32).
// ---------------------------------------------------------------------------
__global__ __launch_bounds__(256) void gru_kernel(
    const bf16* __restrict__ gin, const bf16* __restrict__ hbf,
    const bf16* __restrict__ Wih, const bf16* __restrict__ Whh,
    const float* __restrict__ bih, const float* __restrict__ bhh,
    const float* __restrict__ hold, float* __restrict__ hnew,
    bf16* __restrict__ hnewbf) {
    const int tid = threadIdx.x;
    const int wave = tid >> 6, lane = tid & 63;
    const int wm = wave >> 1, wn = wave & 1;
    const int quad = lane >> 4, r = lane & 15;
    const int kq = quad * 8;

    const int m0 = blockIdx.y * 32 + wm * 16 + r;
    const int n0 = blockIdx.x * 64 + wn * 32;

    const bf16* grow = gin + (long)m0 * H + kq;
    const bf16* hrow = hbf + (long)m0 * H + kq;

    const bf16* wi[3][2];
    const bf16* wh[3][2];
#pragma unroll
    for (int g = 0; g < 3; ++g)
#pragma unroll
        for (int ni = 0; ni < 2; ++ni) {
            const long row = (long)g * H + n0 + ni * 16 + r;
            wi[g][ni] = Wih + row * H + kq;
            wh[g][ni] = Whh + row * H + kq;
        }

    f32x4 aI[3][2], aH[3][2];
#pragma unroll
    for (int g = 0; g < 3; ++g)
#pragma unroll
        for (int ni = 0; ni < 2; ++ni) {
            aI[g][ni] = (f32x4){0.f, 0.f, 0.f, 0.f};
            aH[g][ni] = (f32x4){0.f, 0.f, 0.f, 0.f};
        }

#pragma unroll 2
    for (int k = 0; k < H; k += 32) {
        bf16x8 ai = *(const bf16x8*)(grow + k);
        bf16x8 ah = *(const bf16x8*)(hrow + k);
#pragma unroll
        for (int g = 0; g < 3; ++g)
#pragma unroll
            for (int ni = 0; ni < 2; ++ni) {
                bf16x8 bi = *(const bf16x8*)(wi[g][ni] + k);
                aI[g][ni] = __builtin_amdgcn_mfma_f32_16x16x32_bf16(ai, bi, aI[g][ni], 0, 0, 0);
                bf16x8 bh = *(const bf16x8*)(wh[g][ni] + k);
                aH[g][ni] = __builtin_amdgcn_mfma_f32_16x16x32_bf16(ah, bh, aH[g][ni], 0, 0, 0);
            }
    }

    const int mbase = blockIdx.y * 32 + wm * 16 + quad * 4;
#pragma unroll
    for (int ni = 0; ni < 2; ++ni) {
        const int j = n0 + ni * 16 + r;
        const float bir = bih[j], biz = bih[j + H], bin = bih[j + 2 * H];
        const float bhr = bhh[j], bhz = bhh[j + H], bhn = bhh[j + 2 * H];
#pragma unroll
        for (int reg = 0; reg < 4; ++reg) {
            const int m = mbase + reg;
            const float gir = aI[0][ni][reg] + bir, ghr = aH[0][ni][reg] + bhr;
            const float giz = aI[1][ni][reg] + biz, ghz = aH[1][ni][reg] + bhz;
            const float ginv = aI[2][ni][reg] + bin, ghn = aH[2][ni][reg] + bhn;
            const float rg = 1.f / (1.f + __expf(-(gir + ghr)));
            const float zg = 1.f / (1.f + __expf(-(giz + ghz)));
            const float ng = tanhf(ginv + rg * ghn);
            const long idx = (long)m * H + j;
            const float hv = hold[idx];
            const float hnv = (1.f - zg) * ng + zg * hv;
            hnew[idx] = hnv;
            hnewbf[idx] = f2bf(hnv);
        }
    }
}

// ---------------------------------------------------------------------------
// Precompute: D_bf16 = A@Bmat (+ beta*C0). fp32 LDS-tiled. grid (N/32, M/32).
// ---------------------------------------------------------------------------
__global__ __launch_bounds__(256) void sgemm_bf16out(
    const float* __restrict__ A, int lda, const float* __restrict__ Bm, int ldb,
    const float* __restrict__ C0, int ldc0, float beta,
    bf16* __restrict__ D, int ldd, int M, int K) {
    __shared__ float As[32][33], Bs[32][33];
    const int tx = threadIdx.x & 15, ty = threadIdx.x >> 4;
    const int bx = blockIdx.x * 32, by = blockIdx.y * 32;
    float acc[2][2] = {{0.f, 0.f}, {0.f, 0.f}};
    for (int k0 = 0; k0 < K; k0 += 32) {
        for (int i = threadIdx.x; i < 1024; i += 256) {
            const int rr = i >> 5, cc = i & 31;
            const int gr = by + rr;
            As[rr][cc] = (gr < M) ? A[(long)gr * lda + k0 + cc] : 0.f;
            Bs[rr][cc] = Bm[(long)(k0 + rr) * ldb + bx + cc];
        }
        __syncthreads();
#pragma unroll
        for (int kk = 0; kk < 32; ++kk) {
            const float a0 = As[ty * 2][kk], a1 = As[ty * 2 + 1][kk];
            const float b0 = Bs[kk][tx * 2], b1 = Bs[kk][tx * 2 + 1];
            acc[0][0] += a0 * b0; acc[0][1] += a0 * b1;
            acc[1][0] += a1 * b0; acc[1][1] += a1 * b1;
        }
        __syncthreads();
    }
#pragma unroll
    for (int i = 0; i < 2; ++i)
#pragma unroll
        for (int j = 0; j < 2; ++j) {
            const int gr = by + ty * 2 + i, gc = bx + tx * 2 + j;
            if (gr < M) {
                float v = acc[i][j];
                if (C0) v += beta * C0[(long)gr * ldc0 + gc];
                D[(long)gr * ldd + gc] = f2bf(v);
            }
        }
}

// dst[j] = bsrc[j] + dot(Wsrc[j, 0:1024], bo)
__global__ __launch_bounds__(256) void bias_dot_kernel(
    const float* __restrict__ Wsrc, int ld, const float* __restrict__ bsrc,
    const float* __restrict__ bo, float* __restrict__ dst, int n) {
    const int j = blockIdx.x * 256 + threadIdx.x;
    if (j >= n) return;
    float s = bsrc[j];
    const float* row = Wsrc + (long)j * ld;
    for (int m = 0; m < 1024; ++m) s += row[m] * bo[m];
    dst[j] = s;
}

// ---------------------------------------------------------------------------
__global__ __launch_bounds__(256) void cast_kernel(
    const float* __restrict__ src, bf16* __restrict__ dst, long n4) {
    long i = (long)blockIdx.x * blockDim.x + threadIdx.x;
    const long stride = (long)gridDim.x * blockDim.x;
    for (; i < n4; i += stride) {
        float4 v = ((const float4*)src)[i];
        bf16x4 o = {f2bf(v.x), f2bf(v.y), f2bf(v.z), f2bf(v.w)};
        *(bf16x4*)(dst + 4 * i) = o;
    }
}

__global__ __launch_bounds__(256) void init_h_kernel(
    const float* __restrict__ h0, float* __restrict__ hfp,
    bf16* __restrict__ hbf, long n4) {
    long i = (long)blockIdx.x * blockDim.x + threadIdx.x;
    const long stride = (long)gridDim.x * blockDim.x;
    for (; i < n4; i += stride) {
        float4 v = ((const float4*)h0)[i];
        ((float4*)hfp)[i] = v;
        bf16x4 o = {f2bf(v.x), f2bf(v.y), f2bf(v.z), f2bf(v.w)};
        *(bf16x4*)(hbf + 4 * i) = o;
    }
}

__global__ __launch_bounds__(256) void copy_f32_kernel(
    const float* __restrict__ src, float* __restrict__ dst, long n4) {
    long i = (long)blockIdx.x * blockDim.x + threadIdx.x;
    const long stride = (long)gridDim.x * blockDim.x;
    for (; i < n4; i += stride) ((float4*)dst)[i] = ((const float4*)src)[i];
}

// ---------------------------------------------------------------------------
extern "C" void kernel_launch(void* const* d_in, const int* in_sizes, int n_in,
                              void* d_out, int out_size, void* d_ws, size_t ws_size,
                              hipStream_t stream) {
    const float* enc_f = (const float*)d_in[0];
    const float* hidden = (const float*)d_in[1];
    const float* Wa = (const float*)d_in[3];
    const float* ba = (const float*)d_in[4];
    const float* Wc = (const float*)d_in[5];
    const float* bc = (const float*)d_in[6];
    const float* Wih = (const float*)d_in[7];
    const float* Whh = (const float*)d_in[8];
    const float* bih = (const float*)d_in[9];
    const float* bhh = (const float*)d_in[10];
    const float* Wo = (const float*)d_in[11];
    const float* bo = (const float*)d_in[12];
    float* out = (float*)d_out;

    char* p = (char*)d_ws;
    auto carve = [&](long bytes) {
        char* q = p;
        p += (bytes + 255) & ~255L;
        return q;
    };
    bf16* Wa_bf   = (bf16*)carve((long)ATT * 2048 * 2);
    bf16* Wc_bf   = (bf16*)carve((long)H * 2048 * 2);
    bf16* Wih_bf  = (bf16*)carve((long)3 * H * H * 2);
    bf16* Whh_bf  = (bf16*)carve((long)3 * H * H * 2);
    bf16* Wo_bf   = (bf16*)carve((long)O * H * 2);
    bf16* Wd_bf   = (bf16*)carve((long)H * H * 2);
    bf16* Waeff_bf = (bf16*)carve((long)ATT * H * 2);
    bf16* enc_bf  = (bf16*)carve((long)B * S * 1024 * 2);
    bf16* attn_w  = (bf16*)carve((long)B * 64 * 2);
    bf16* attn_bf = (bf16*)carve((long)B * 1024 * 2);
    bf16* gru_bf  = (bf16*)carve((long)B * H * 2);
    float* hfpA   = (float*)carve((long)B * H * 4);
    float* hfpB   = (float*)carve((long)B * H * 4);
    float* ba_eff = (float*)carve((long)ATT * 4);
    float* bc_eff = (float*)carve((long)H * 4);

    const long hall_bytes = (long)(T + 1) * B * H * 2;
    const long used = (long)(p - (char*)d_ws);
    const bool hall = ((long)ws_size - used) >= (hall_bytes + 4096);
    bf16* Hall = nullptr; bf16* hbfA = nullptr; bf16* hbfB = nullptr;
    if (hall) {
        Hall = (bf16*)carve(hall_bytes);
    } else {
        hbfA = (bf16*)carve((long)B * H * 2);
        hbfB = (bf16*)carve((long)B * H * 2);
    }

    auto cast = [&](const float* s, bf16* d, long n) {
        long n4 = n / 4;
        int blocks = (int)((n4 + 255) / 256);
        if (blocks > 4096) blocks = 4096;
        cast_kernel<<<blocks, 256, 0, stream>>>(s, d, n4);
    };
    cast(Wa, Wa_bf, (long)ATT * 2048);
    cast(Wc, Wc_bf, (long)H * 2048);
    cast(Wih, Wih_bf, (long)3 * H * H);
    cast(Whh, Whh_bf, (long)3 * H * H);
    cast(Wo, Wo_bf, (long)O * H);
    cast(enc_f, enc_bf, (long)B * S * 1024);
    init_h_kernel<<<512, 256, 0, stream>>>(hidden, hfpA,
                                           hall ? Hall : hbfA, (long)B * H / 4);

    // Wd = WcL @ Wo   (fp32, bf16 out)
    sgemm_bf16out<<<dim3(32, 32), 256, 0, stream>>>(
        Wc, 2048, Wo, 1024, nullptr, 0, 0.f, Wd_bf, 1024, 1024, 1024);
    // Wa_eff = WaL @ Wo + WaR
    sgemm_bf16out<<<dim3(32, 2), 256, 0, stream>>>(
        Wa, 2048, Wo, 1024, Wa + 1024, 2048, 1.f, Waeff_bf, 1024, 64, 1024);
    bias_dot_kernel<<<4, 256, 0, stream>>>(Wc, 2048, bc, bo, bc_eff, 1024);
    bias_dot_kernel<<<1, 256, 0, stream>>>(Wa, 2048, ba, bo, ba_eff, 64);

    const dim3 blk(256);
    const dim3 grid_gemm(H / 64, B / 32);  // (16,16)
    const dim3 grid_lg(1, B / 16);         // (1,32)

    for (int t = 0; t < T; ++t) {
        const bf16* hbf_r = hall ? (Hall + (long)t * B * H)
                                 : ((t & 1) ? hbfB : hbfA);
        bf16* hbf_w = hall ? (Hall + (long)(t + 1) * B * H)
                           : ((t & 1) ? hbfA : hbfB);
        const float* hfp_r = (t & 1) ? hfpB : hfpA;
        float* hfp_w = (t & 1) ? hfpA : hfpB;

        if (t == 0)
            attn_logits_kernel<<<grid_lg, 128, 0, stream>>>(
                hbf_r, Wa_bf + 1024, 2048, ba, attn_w);
        else
            attn_logits_kernel<<<grid_lg, 128, 0, stream>>>(
                hbf_r, Waeff_bf, 1024, ba_eff, attn_w);

        attn_apply_kernel<<<B, blk, 0, stream>>>(attn_w, enc_bf, attn_bf);

        if (t == 0)
            combine_kernel<0><<<grid_gemm, blk, 0, stream>>>(
                hbf_r, Wd_bf, attn_bf, Wc_bf + 1024, 2048, bc, gru_bf);
        else
            combine_kernel<1024><<<grid_gemm, blk, 0, stream>>>(
                hbf_r, Wd_bf, attn_bf, Wc_bf + 1024, 2048, bc_eff, gru_bf);

        gru_kernel<<<grid_gemm, blk, 0, stream>>>(
            gru_bf, hbf_r, Wih_bf, Whh_bf, bih, bhh, hfp_r, hfp_w, hbf_w);

        if (!hall)
            fc_kernel<false><<<grid_gemm, blk, 0, stream>>>(
                hbf_w, Wo_bf, bo, out + (long)t * O, (long)T * O);
    }

    if (hall)
        fc_kernel<true><<<dim3(O / 64, (T * B) / 32), blk, 0, stream>>>(
            Hall + (long)B * H, Wo_bf, bo, out, 0);

    copy_f32_kernel<<<512, 256, 0, stream>>>(hfpA, out + (long)B * T * O,
                                             (long)B * H / 4);
}